// Round 1
// baseline (606.902 us; speedup 1.0000x reference)
//
#include <hip/hip_runtime.h>
#include <hip/hip_bf16.h>

// LocalDualDirectedMessagePassingLayer on MI355X (gfx950)
// Strategy: bf16 MFMA (16x16x32) for all GEMMs, fp32 accumulate.
//  - pack_weights: fragment-major bf16 packing of W_read/W_msg/W_agg/W_upd/W_write
//  - edge_kernel : 64 edges/block; gather->GEMM(read)->relu->GEMM(msg)->relu->
//                  sorted-segment reduce -> atomicAdd into msg_sum; fused copy
//                  node_memory -> out (overlaps copy BW with MFMA of other blocks)
//  - dest_kernel : 32 dests/block; counts by binary search on sorted dest_seg;
//                  GEMM chain (read/agg/upd/write) -> tanh -> scatter to out[node_ids]

typedef __bf16 bf16_t;
typedef __bf16 bf16x4 __attribute__((ext_vector_type(4)));
typedef __bf16 bf16x8 __attribute__((ext_vector_type(8)));
typedef float  f32x4  __attribute__((ext_vector_type(4)));

#define NNODES 200000
#define NDEST  8192
#define NEDGE  262144

// ---------------- weight packing ----------------
// packed[p], p = ((kb*8 + nb)*64 + lane)*8 + j
//   <- W[(kb*32 + (lane>>4)*8 + j)*128 + nb*16 + (lane&15)]
// so a wave's B-fragment load for MFMA tile (kb, nb) is one coalesced 16B/lane load.
__global__ void pack_weights_kernel(const float* __restrict__ Wr, const float* __restrict__ Wm,
                                    const float* __restrict__ Wa, const float* __restrict__ Wu,
                                    const float* __restrict__ Ww,
                                    bf16_t* __restrict__ Pr, bf16_t* __restrict__ Pm,
                                    bf16_t* __restrict__ Pa, bf16_t* __restrict__ Pu,
                                    bf16_t* __restrict__ Pw) {
    int p = blockIdx.x * 256 + threadIdx.x;
    const float* src; bf16_t* dst; int rel;
    if (p < 32768)       { src = Wr; dst = Pr; rel = p; }
    else if (p < 61440)  { src = Wm; dst = Pm; rel = p - 32768; }
    else if (p < 94208)  { src = Wa; dst = Pa; rel = p - 61440; }
    else if (p < 126976) { src = Wu; dst = Pu; rel = p - 94208; }
    else if (p < 143360) { src = Ww; dst = Pw; rel = p - 126976; }
    else return;
    int j    = rel & 7;
    int lane = (rel >> 3) & 63;
    int t    = rel >> 9;
    int nb   = t & 7;
    int kb   = t >> 3;
    int row  = kb * 32 + ((lane >> 4) << 3) + j;
    int col  = nb * 16 + (lane & 15);
    dst[rel] = (bf16_t)src[row * 128 + col];
}

// ---------------- edge phase ----------------
__global__ __launch_bounds__(256, 2) void edge_kernel(
    const float* __restrict__ node_memory, const float* __restrict__ node_features,
    const float* __restrict__ edge_features, const float* __restrict__ time_enc,
    const int* __restrict__ source_ids, const int* __restrict__ edge_ids,
    const int* __restrict__ dest_seg,
    const bf16_t* __restrict__ Pr, const bf16_t* __restrict__ Pm,
    const float* __restrict__ b_read, const float* __restrict__ b_msg,
    float* __restrict__ msg_sum, float* __restrict__ out) {

    // A1: [64 x 264] bf16 src inputs (stride 264 => 2-way LDS aliasing only, free)
    //     later aliased as Msg f32[64 x 132] (same 33792 bytes)
    __shared__ __align__(16) bf16_t A1[64 * 264];
    __shared__ __align__(16) bf16_t A2[64 * 232];   // msg inputs [src_read|edge_feat|time]
    __shared__ int s_src[64], s_dst[64], s_eid[64];

    const int tid = threadIdx.x;
    const int e0  = blockIdx.x * 64;

    if (tid < 64) {
        s_src[tid] = source_ids[e0 + tid];
        s_dst[tid] = dest_seg[e0 + tid];
        s_eid[tid] = edge_ids[e0 + tid];
    }
    __syncthreads();

    // gather [mem|feat] -> A1 bf16 (each wave covers one full 1KB edge row: coalesced)
    #pragma unroll
    for (int i = 0; i < 16; ++i) {
        int c  = i * 256 + tid;
        int m  = c >> 6;
        int kc = (c & 63) << 2;
        int nrow = s_src[m];
        float4 v = (kc < 128)
            ? *(const float4*)(node_memory   + (size_t)nrow * 128 + kc)
            : *(const float4*)(node_features + (size_t)nrow * 128 + (kc - 128));
        bf16x4 pv = { (bf16_t)v.x, (bf16_t)v.y, (bf16_t)v.z, (bf16_t)v.w };
        *(bf16x4*)(A1 + m * 264 + kc) = pv;
    }
    // edge features -> A2 cols 128..191
    #pragma unroll
    for (int i = 0; i < 4; ++i) {
        int c  = i * 256 + tid;
        int m  = c >> 4;
        int kc = (c & 15) << 2;
        float4 v = *(const float4*)(edge_features + (size_t)s_eid[m] * 64 + kc);
        bf16x4 pv = { (bf16_t)v.x, (bf16_t)v.y, (bf16_t)v.z, (bf16_t)v.w };
        *(bf16x4*)(A2 + m * 232 + 128 + kc) = pv;
    }
    // time encodings -> A2 cols 192..223
    #pragma unroll
    for (int i = 0; i < 2; ++i) {
        int c  = i * 256 + tid;
        int m  = c >> 3;
        int kc = (c & 7) << 2;
        float4 v = *(const float4*)(time_enc + (size_t)(e0 + m) * 32 + kc);
        bf16x4 pv = { (bf16_t)v.x, (bf16_t)v.y, (bf16_t)v.z, (bf16_t)v.w };
        *(bf16x4*)(A2 + m * 232 + 192 + kc) = pv;
    }
    __syncthreads();

    const int lane = tid & 63;
    const int w    = tid >> 6;
    const int quad = lane >> 4;
    const int lq   = lane & 15;
    const int n0   = w * 32;          // wave's 32-column slice of N=128

    // ---- GEMM1: A1[64x256] @ W_read[256x128] ----
    f32x4 acc[4][2] = {};
    #pragma unroll
    for (int kb = 0; kb < 8; ++kb) {
        bf16x8 b0 = *(const bf16x8*)(Pr + (((kb * 8 + (w * 2 + 0)) * 64 + lane) << 3));
        bf16x8 b1 = *(const bf16x8*)(Pr + (((kb * 8 + (w * 2 + 1)) * 64 + lane) << 3));
        #pragma unroll
        for (int mt = 0; mt < 4; ++mt) {
            bf16x8 a = *(const bf16x8*)(A1 + (mt * 16 + lq) * 264 + kb * 32 + quad * 8);
            acc[mt][0] = __builtin_amdgcn_mfma_f32_16x16x32_bf16(a, b0, acc[mt][0], 0, 0, 0);
            acc[mt][1] = __builtin_amdgcn_mfma_f32_16x16x32_bf16(a, b1, acc[mt][1], 0, 0, 0);
        }
    }
    {   // bias + relu -> A2 cols 0..127 (bf16), C-layout: row = quad*4+r, col = lane&15
        float bb0 = b_read[n0 + lq];
        float bb1 = b_read[n0 + 16 + lq];
        #pragma unroll
        for (int mt = 0; mt < 4; ++mt)
            #pragma unroll
            for (int nt = 0; nt < 2; ++nt) {
                float bb = nt ? bb1 : bb0;
                #pragma unroll
                for (int r = 0; r < 4; ++r) {
                    float v = fmaxf(acc[mt][nt][r] + bb, 0.f);
                    A2[(mt * 16 + quad * 4 + r) * 232 + (n0 + nt * 16 + lq)] = (bf16_t)v;
                }
            }
    }
    __syncthreads();

    // ---- GEMM2: A2[64x224] @ W_msg[224x128] ----
    f32x4 acc2[4][2] = {};
    #pragma unroll
    for (int kb = 0; kb < 7; ++kb) {
        bf16x8 b0 = *(const bf16x8*)(Pm + (((kb * 8 + (w * 2 + 0)) * 64 + lane) << 3));
        bf16x8 b1 = *(const bf16x8*)(Pm + (((kb * 8 + (w * 2 + 1)) * 64 + lane) << 3));
        #pragma unroll
        for (int mt = 0; mt < 4; ++mt) {
            bf16x8 a = *(const bf16x8*)(A2 + (mt * 16 + lq) * 232 + kb * 32 + quad * 8);
            acc2[mt][0] = __builtin_amdgcn_mfma_f32_16x16x32_bf16(a, b0, acc2[mt][0], 0, 0, 0);
            acc2[mt][1] = __builtin_amdgcn_mfma_f32_16x16x32_bf16(a, b1, acc2[mt][1], 0, 0, 0);
        }
    }
    float* Msg = (float*)A1;   // alias: A1 is dead after GEMM1 (barrier passed)
    {
        float bb0 = b_msg[n0 + lq];
        float bb1 = b_msg[n0 + 16 + lq];
        #pragma unroll
        for (int mt = 0; mt < 4; ++mt)
            #pragma unroll
            for (int nt = 0; nt < 2; ++nt) {
                float bb = nt ? bb1 : bb0;
                #pragma unroll
                for (int r = 0; r < 4; ++r) {
                    float v = fmaxf(acc2[mt][nt][r] + bb, 0.f);
                    Msg[(mt * 16 + quad * 4 + r) * 132 + (n0 + nt * 16 + lq)] = v;
                }
            }
    }
    __syncthreads();

    // ---- sorted-segment reduce: run-length sum then one atomic per run ----
    if (tid < 128) {   // thread = column
        int cur = s_dst[0];
        float run = 0.f;
        for (int m = 0; m < 64; ++m) {
            int d = s_dst[m];
            if (d != cur) {
                atomicAdd(msg_sum + (size_t)cur * 128 + tid, run);
                run = 0.f; cur = d;
            }
            run += Msg[m * 132 + tid];
        }
        atomicAdd(msg_sum + (size_t)cur * 128 + tid, run);
    }

    // ---- fused copy node_memory -> out (overlaps with other blocks' MFMA) ----
    {
        const float4* s4 = (const float4*)node_memory;
        float4* d4 = (float4*)out;
        const int total4 = (NNODES * 128) / 4;   // 6,400,000
        const int stride = gridDim.x * 256;
        for (int i = blockIdx.x * 256 + tid; i < total4; i += stride)
            d4[i] = s4[i];
    }
}

// ---------------- destination phase ----------------
__global__ __launch_bounds__(256, 2) void dest_kernel(
    const float* __restrict__ node_memory, const float* __restrict__ node_features,
    const int* __restrict__ node_ids, const int* __restrict__ dest_seg,
    const bf16_t* __restrict__ Pr, const bf16_t* __restrict__ Pa,
    const bf16_t* __restrict__ Pu, const bf16_t* __restrict__ Pw,
    const float* __restrict__ b_read, const float* __restrict__ b_agg,
    const float* __restrict__ b_upd, const float* __restrict__ b_write,
    const float* __restrict__ msg_sum, float* __restrict__ out) {

    __shared__ __align__(16) bf16_t B1[32 * 264];  // [mem|feat] -> agg(0..127) & upd(128..255)
    __shared__ __align__(16) bf16_t B2[32 * 264];  // [dst_read(0..127) | msg_mean(128..255)]
    __shared__ int   s_nid[32];
    __shared__ int   s_lb[64];
    __shared__ float s_inv[32];

    const int tid = threadIdx.x;
    const int s0  = blockIdx.x * 32;

    if (tid < 32) s_nid[tid] = node_ids[s0 + tid];
    if (tid < 64) {      // counts via binary search in sorted dest_seg
        int t = tid & 31, half = tid >> 5;
        int target = s0 + t + half;
        int lo = 0, hi = NEDGE;
        while (lo < hi) { int mid = (lo + hi) >> 1; if (dest_seg[mid] < target) lo = mid + 1; else hi = mid; }
        s_lb[tid] = lo;
    }
    __syncthreads();
    if (tid < 32) {
        int cnt = s_lb[tid + 32] - s_lb[tid];
        s_inv[tid] = 1.f / (float)(cnt > 1 ? cnt : 1);
    }
    // gather [mem|feat] -> B1
    #pragma unroll
    for (int i = 0; i < 8; ++i) {
        int c = i * 256 + tid; int m = c >> 6; int kc = (c & 63) << 2;
        int nrow = s_nid[m];
        float4 v = (kc < 128)
            ? *(const float4*)(node_memory   + (size_t)nrow * 128 + kc)
            : *(const float4*)(node_features + (size_t)nrow * 128 + (kc - 128));
        bf16x4 pv = { (bf16_t)v.x, (bf16_t)v.y, (bf16_t)v.z, (bf16_t)v.w };
        *(bf16x4*)(B1 + m * 264 + kc) = pv;
    }
    __syncthreads();   // B1 + s_inv ready
    // msg_mean -> B2 cols 128..255
    #pragma unroll
    for (int i = 0; i < 4; ++i) {
        int c = i * 256 + tid; int m = c >> 5; int kc = (c & 31) << 2;
        float4 v = *(const float4*)(msg_sum + (size_t)(s0 + m) * 128 + kc);
        float inv = s_inv[m];
        bf16x4 pv = { (bf16_t)(v.x * inv), (bf16_t)(v.y * inv), (bf16_t)(v.z * inv), (bf16_t)(v.w * inv) };
        *(bf16x4*)(B2 + m * 264 + 128 + kc) = pv;
    }

    const int lane = tid & 63;
    const int w    = tid >> 6;
    const int quad = lane >> 4;
    const int lq   = lane & 15;
    const int n0   = w * 32;

    // GEMM1: [mem|feat] @ W_read -> dst_read -> B2 cols 0..127
    {
        f32x4 acc[2][2] = {};
        #pragma unroll
        for (int kb = 0; kb < 8; ++kb) {
            bf16x8 b0 = *(const bf16x8*)(Pr + (((kb * 8 + (w * 2 + 0)) * 64 + lane) << 3));
            bf16x8 b1 = *(const bf16x8*)(Pr + (((kb * 8 + (w * 2 + 1)) * 64 + lane) << 3));
            #pragma unroll
            for (int mt = 0; mt < 2; ++mt) {
                bf16x8 a = *(const bf16x8*)(B1 + (mt * 16 + lq) * 264 + kb * 32 + quad * 8);
                acc[mt][0] = __builtin_amdgcn_mfma_f32_16x16x32_bf16(a, b0, acc[mt][0], 0, 0, 0);
                acc[mt][1] = __builtin_amdgcn_mfma_f32_16x16x32_bf16(a, b1, acc[mt][1], 0, 0, 0);
            }
        }
        float bb0 = b_read[n0 + lq], bb1 = b_read[n0 + 16 + lq];
        #pragma unroll
        for (int mt = 0; mt < 2; ++mt)
            #pragma unroll
            for (int nt = 0; nt < 2; ++nt) {
                float bb = nt ? bb1 : bb0;
                #pragma unroll
                for (int r = 0; r < 4; ++r) {
                    float v = fmaxf(acc[mt][nt][r] + bb, 0.f);
                    B2[(mt * 16 + quad * 4 + r) * 264 + (n0 + nt * 16 + lq)] = (bf16_t)v;
                }
            }
    }
    __syncthreads();

    // GEMM2: [dst_read|msg_mean] @ W_agg -> agg -> B1 cols 0..127
    {
        f32x4 acc[2][2] = {};
        #pragma unroll
        for (int kb = 0; kb < 8; ++kb) {
            bf16x8 b0 = *(const bf16x8*)(Pa + (((kb * 8 + (w * 2 + 0)) * 64 + lane) << 3));
            bf16x8 b1 = *(const bf16x8*)(Pa + (((kb * 8 + (w * 2 + 1)) * 64 + lane) << 3));
            #pragma unroll
            for (int mt = 0; mt < 2; ++mt) {
                bf16x8 a = *(const bf16x8*)(B2 + (mt * 16 + lq) * 264 + kb * 32 + quad * 8);
                acc[mt][0] = __builtin_amdgcn_mfma_f32_16x16x32_bf16(a, b0, acc[mt][0], 0, 0, 0);
                acc[mt][1] = __builtin_amdgcn_mfma_f32_16x16x32_bf16(a, b1, acc[mt][1], 0, 0, 0);
            }
        }
        float bb0 = b_agg[n0 + lq], bb1 = b_agg[n0 + 16 + lq];
        #pragma unroll
        for (int mt = 0; mt < 2; ++mt)
            #pragma unroll
            for (int nt = 0; nt < 2; ++nt) {
                float bb = nt ? bb1 : bb0;
                #pragma unroll
                for (int r = 0; r < 4; ++r) {
                    float v = fmaxf(acc[mt][nt][r] + bb, 0.f);
                    B1[(mt * 16 + quad * 4 + r) * 264 + (n0 + nt * 16 + lq)] = (bf16_t)v;
                }
            }
    }
    __syncthreads();

    // GEMM3: [agg|dst_read] @ W_upd -> upd -> B1 cols 128..255
    {
        f32x4 acc[2][2] = {};
        #pragma unroll
        for (int kb = 0; kb < 8; ++kb) {
            bf16x8 b0 = *(const bf16x8*)(Pu + (((kb * 8 + (w * 2 + 0)) * 64 + lane) << 3));
            bf16x8 b1 = *(const bf16x8*)(Pu + (((kb * 8 + (w * 2 + 1)) * 64 + lane) << 3));
            #pragma unroll
            for (int mt = 0; mt < 2; ++mt) {
                bf16x8 a = (kb < 4)
                    ? *(const bf16x8*)(B1 + (mt * 16 + lq) * 264 + kb * 32 + quad * 8)
                    : *(const bf16x8*)(B2 + (mt * 16 + lq) * 264 + (kb - 4) * 32 + quad * 8);
                acc[mt][0] = __builtin_amdgcn_mfma_f32_16x16x32_bf16(a, b0, acc[mt][0], 0, 0, 0);
                acc[mt][1] = __builtin_amdgcn_mfma_f32_16x16x32_bf16(a, b1, acc[mt][1], 0, 0, 0);
            }
        }
        float bb0 = b_upd[n0 + lq], bb1 = b_upd[n0 + 16 + lq];
        #pragma unroll
        for (int mt = 0; mt < 2; ++mt)
            #pragma unroll
            for (int nt = 0; nt < 2; ++nt) {
                float bb = nt ? bb1 : bb0;
                #pragma unroll
                for (int r = 0; r < 4; ++r) {
                    float v = fmaxf(acc[mt][nt][r] + bb, 0.f);
                    B1[(mt * 16 + quad * 4 + r) * 264 + 128 + (n0 + nt * 16 + lq)] = (bf16_t)v;
                }
            }
    }
    __syncthreads();

    // GEMM4: upd @ W_write (K=128) -> tanh -> scatter to out[node_ids]
    {
        f32x4 acc[2][2] = {};
        #pragma unroll
        for (int kb = 0; kb < 4; ++kb) {
            bf16x8 b0 = *(const bf16x8*)(Pw + (((kb * 8 + (w * 2 + 0)) * 64 + lane) << 3));
            bf16x8 b1 = *(const bf16x8*)(Pw + (((kb * 8 + (w * 2 + 1)) * 64 + lane) << 3));
            #pragma unroll
            for (int mt = 0; mt < 2; ++mt) {
                bf16x8 a = *(const bf16x8*)(B1 + (mt * 16 + lq) * 264 + 128 + kb * 32 + quad * 8);
                acc[mt][0] = __builtin_amdgcn_mfma_f32_16x16x32_bf16(a, b0, acc[mt][0], 0, 0, 0);
                acc[mt][1] = __builtin_amdgcn_mfma_f32_16x16x32_bf16(a, b1, acc[mt][1], 0, 0, 0);
            }
        }
        float bb0 = b_write[n0 + lq], bb1 = b_write[n0 + 16 + lq];
        #pragma unroll
        for (int mt = 0; mt < 2; ++mt)
            #pragma unroll
            for (int nt = 0; nt < 2; ++nt) {
                float bb = nt ? bb1 : bb0;
                #pragma unroll
                for (int r = 0; r < 4; ++r) {
                    int row = mt * 16 + quad * 4 + r;
                    int col = n0 + nt * 16 + lq;
                    out[(size_t)s_nid[row] * 128 + col] = tanhf(acc[mt][nt][r] + bb);
                }
            }
    }
}

extern "C" void kernel_launch(void* const* d_in, const int* in_sizes, int n_in,
                              void* d_out, int out_size, void* d_ws, size_t ws_size,
                              hipStream_t stream) {
    const float* node_memory   = (const float*)d_in[0];
    const float* node_features = (const float*)d_in[1];
    const float* edge_features = (const float*)d_in[2];
    const float* time_enc      = (const float*)d_in[3];
    const int*   node_ids      = (const int*)d_in[4];
    const int*   source_ids    = (const int*)d_in[5];
    const int*   edge_ids      = (const int*)d_in[6];
    const int*   dest_seg      = (const int*)d_in[7];
    const float* W_read  = (const float*)d_in[8];
    const float* b_read  = (const float*)d_in[9];
    const float* W_msg   = (const float*)d_in[10];
    const float* b_msg   = (const float*)d_in[11];
    const float* W_agg   = (const float*)d_in[12];
    const float* b_agg   = (const float*)d_in[13];
    const float* W_upd   = (const float*)d_in[14];
    const float* b_upd   = (const float*)d_in[15];
    const float* W_write = (const float*)d_in[16];
    const float* b_write = (const float*)d_in[17];
    float* out = (float*)d_out;

    char* ws = (char*)d_ws;
    float*  msg_sum = (float*)(ws + 0);                 // 8192*128*4 = 4,194,304 B
    bf16_t* Pr = (bf16_t*)(ws + 4194304);               // 65536 B
    bf16_t* Pm = (bf16_t*)(ws + 4194304 + 65536);       // 57344 B
    bf16_t* Pa = (bf16_t*)(ws + 4194304 + 122880);      // 65536 B
    bf16_t* Pu = (bf16_t*)(ws + 4194304 + 188416);      // 65536 B
    bf16_t* Pw = (bf16_t*)(ws + 4194304 + 253952);      // 32768 B

    hipMemsetAsync(msg_sum, 0, (size_t)NDEST * 128 * sizeof(float), stream);
    pack_weights_kernel<<<560, 256, 0, stream>>>(W_read, W_msg, W_agg, W_upd, W_write,
                                                 Pr, Pm, Pa, Pu, Pw);
    edge_kernel<<<NEDGE / 64, 256, 0, stream>>>(node_memory, node_features, edge_features,
                                                time_enc, source_ids, edge_ids, dest_seg,
                                                Pr, Pm, b_read, b_msg, msg_sum, out);
    dest_kernel<<<NDEST / 32, 256, 0, stream>>>(node_memory, node_features, node_ids, dest_seg,
                                                Pr, Pa, Pu, Pw, b_read, b_agg, b_upd, b_write,
                                                msg_sum, out);
}

// Round 2
// 560.006 us; speedup vs baseline: 1.0837x; 1.0837x over previous
//
#include <hip/hip_runtime.h>
#include <hip/hip_bf16.h>

// LocalDualDirectedMessagePassingLayer on MI355X (gfx950) — round 2
// Changes vs round 1 (which was occupancy-bound: 21% occ, 63.5 KB LDS, 2 blk/CU):
//  - edge_kernel: single phase-aliased LDS buffer S[64x264] (A1 -> A2 -> Msg),
//    edge/time staged in registers across GEMM1  => ~34.6 KB LDS, 4 blk/CU (50% occ)
//  - edge_kernel also accumulates per-dest counts (removes dest binary search)
//  - dest_kernel: 16 dests/block (512 blocks), no binary search, fast tanh

typedef __bf16 bf16_t;
typedef __bf16 bf16x4 __attribute__((ext_vector_type(4)));
typedef __bf16 bf16x8 __attribute__((ext_vector_type(8)));
typedef float  f32x4  __attribute__((ext_vector_type(4)));

#define NNODES 200000
#define NDEST  8192
#define NEDGE  262144

__device__ __forceinline__ float fast_tanh(float x) {
    float e = __expf(2.f * x);
    return 1.f - 2.f / (e + 1.f);
}

// ---------------- weight packing ----------------
// packed[p], p = ((kb*8 + nb)*64 + lane)*8 + j
//   <- W[(kb*32 + (lane>>4)*8 + j)*128 + nb*16 + (lane&15)]
__global__ void pack_weights_kernel(const float* __restrict__ Wr, const float* __restrict__ Wm,
                                    const float* __restrict__ Wa, const float* __restrict__ Wu,
                                    const float* __restrict__ Ww,
                                    bf16_t* __restrict__ Pr, bf16_t* __restrict__ Pm,
                                    bf16_t* __restrict__ Pa, bf16_t* __restrict__ Pu,
                                    bf16_t* __restrict__ Pw) {
    int p = blockIdx.x * 256 + threadIdx.x;
    const float* src; bf16_t* dst; int rel;
    if (p < 32768)       { src = Wr; dst = Pr; rel = p; }
    else if (p < 61440)  { src = Wm; dst = Pm; rel = p - 32768; }
    else if (p < 94208)  { src = Wa; dst = Pa; rel = p - 61440; }
    else if (p < 126976) { src = Wu; dst = Pu; rel = p - 94208; }
    else if (p < 143360) { src = Ww; dst = Pw; rel = p - 126976; }
    else return;
    int j    = rel & 7;
    int lane = (rel >> 3) & 63;
    int t    = rel >> 9;
    int nb   = t & 7;
    int kb   = t >> 3;
    int row  = kb * 32 + ((lane >> 4) << 3) + j;
    int col  = nb * 16 + (lane & 15);
    dst[rel] = (bf16_t)src[row * 128 + col];
}

// ---------------- edge phase ----------------
__global__ __launch_bounds__(256, 4) void edge_kernel(
    const float* __restrict__ node_memory, const float* __restrict__ node_features,
    const float* __restrict__ edge_features, const float* __restrict__ time_enc,
    const int* __restrict__ source_ids, const int* __restrict__ edge_ids,
    const int* __restrict__ dest_seg,
    const bf16_t* __restrict__ Pr, const bf16_t* __restrict__ Pm,
    const float* __restrict__ b_read, const float* __restrict__ b_msg,
    float* __restrict__ msg_sum, float* __restrict__ cnt, float* __restrict__ out) {

    // One buffer, three lives (stride 264 bf16 = 132 dwords; 33792 B):
    //  phase 1: A1 [64 x 256] src [mem|feat] bf16
    //  phase 2: A2 [64 x 224] msg input [src_read|edge|time] bf16
    //  phase 3: Msg f32 [64 x 132]
    __shared__ __align__(16) bf16_t S[64 * 264];
    __shared__ int s_src[64], s_dst[64], s_eid[64];

    const int tid = threadIdx.x;
    const int e0  = blockIdx.x * 64;

    if (tid < 64) {
        s_src[tid] = source_ids[e0 + tid];
        s_dst[tid] = dest_seg[e0 + tid];
        s_eid[tid] = edge_ids[e0 + tid];
    }
    __syncthreads();

    // edge feats + time encodings -> registers (written to LDS after GEMM1)
    bf16x4 r_e[4], r_t[2];
    #pragma unroll
    for (int i = 0; i < 4; ++i) {
        int c = i * 256 + tid; int m = c >> 4; int kc = (c & 15) << 2;
        float4 v = *(const float4*)(edge_features + (size_t)s_eid[m] * 64 + kc);
        r_e[i] = bf16x4{ (bf16_t)v.x, (bf16_t)v.y, (bf16_t)v.z, (bf16_t)v.w };
    }
    #pragma unroll
    for (int i = 0; i < 2; ++i) {
        int c = i * 256 + tid; int m = c >> 3; int kc = (c & 7) << 2;
        float4 v = *(const float4*)(time_enc + (size_t)(e0 + m) * 32 + kc);
        r_t[i] = bf16x4{ (bf16_t)v.x, (bf16_t)v.y, (bf16_t)v.z, (bf16_t)v.w };
    }

    // gather [mem|feat] -> S (phase A1); one full 1KB row per wave per iter
    #pragma unroll
    for (int i = 0; i < 16; ++i) {
        int c  = i * 256 + tid;
        int m  = c >> 6;
        int kc = (c & 63) << 2;
        int nrow = s_src[m];
        float4 v = (kc < 128)
            ? *(const float4*)(node_memory   + (size_t)nrow * 128 + kc)
            : *(const float4*)(node_features + (size_t)nrow * 128 + (kc - 128));
        *(bf16x4*)(S + m * 264 + kc) = bf16x4{ (bf16_t)v.x, (bf16_t)v.y, (bf16_t)v.z, (bf16_t)v.w };
    }
    __syncthreads();

    const int lane = tid & 63;
    const int w    = tid >> 6;
    const int quad = lane >> 4;
    const int lq   = lane & 15;
    const int n0   = w * 32;

    // ---- GEMM1: A1[64x256] @ W_read[256x128] ----
    f32x4 acc[4][2] = {};
    #pragma unroll
    for (int kb = 0; kb < 8; ++kb) {
        bf16x8 b0 = *(const bf16x8*)(Pr + (((kb * 8 + (w * 2 + 0)) * 64 + lane) << 3));
        bf16x8 b1 = *(const bf16x8*)(Pr + (((kb * 8 + (w * 2 + 1)) * 64 + lane) << 3));
        #pragma unroll
        for (int mt = 0; mt < 4; ++mt) {
            bf16x8 a = *(const bf16x8*)(S + (mt * 16 + lq) * 264 + kb * 32 + quad * 8);
            acc[mt][0] = __builtin_amdgcn_mfma_f32_16x16x32_bf16(a, b0, acc[mt][0], 0, 0, 0);
            acc[mt][1] = __builtin_amdgcn_mfma_f32_16x16x32_bf16(a, b1, acc[mt][1], 0, 0, 0);
        }
    }
    __syncthreads();   // A1 dead

    // ---- write A2 (phase 2): relu(read) cols 0..127, edge 128..191, time 192..223
    #pragma unroll
    for (int i = 0; i < 4; ++i) {
        int c = i * 256 + tid; int m = c >> 4; int kc = (c & 15) << 2;
        *(bf16x4*)(S + m * 264 + 128 + kc) = r_e[i];
    }
    #pragma unroll
    for (int i = 0; i < 2; ++i) {
        int c = i * 256 + tid; int m = c >> 3; int kc = (c & 7) << 2;
        *(bf16x4*)(S + m * 264 + 192 + kc) = r_t[i];
    }
    {
        float bb0 = b_read[n0 + lq];
        float bb1 = b_read[n0 + 16 + lq];
        #pragma unroll
        for (int mt = 0; mt < 4; ++mt)
            #pragma unroll
            for (int nt = 0; nt < 2; ++nt) {
                float bb = nt ? bb1 : bb0;
                #pragma unroll
                for (int r = 0; r < 4; ++r) {
                    float v = fmaxf(acc[mt][nt][r] + bb, 0.f);
                    S[(mt * 16 + quad * 4 + r) * 264 + (n0 + nt * 16 + lq)] = (bf16_t)v;
                }
            }
    }
    __syncthreads();

    // ---- GEMM2: A2[64x224] @ W_msg[224x128] ----
    f32x4 acc2[4][2] = {};
    #pragma unroll
    for (int kb = 0; kb < 7; ++kb) {
        bf16x8 b0 = *(const bf16x8*)(Pm + (((kb * 8 + (w * 2 + 0)) * 64 + lane) << 3));
        bf16x8 b1 = *(const bf16x8*)(Pm + (((kb * 8 + (w * 2 + 1)) * 64 + lane) << 3));
        #pragma unroll
        for (int mt = 0; mt < 4; ++mt) {
            bf16x8 a = *(const bf16x8*)(S + (mt * 16 + lq) * 264 + kb * 32 + quad * 8);
            acc2[mt][0] = __builtin_amdgcn_mfma_f32_16x16x32_bf16(a, b0, acc2[mt][0], 0, 0, 0);
            acc2[mt][1] = __builtin_amdgcn_mfma_f32_16x16x32_bf16(a, b1, acc2[mt][1], 0, 0, 0);
        }
    }
    __syncthreads();   // A2 dead

    // ---- phase 3: Msg f32 [64 x 132]
    float* Msg = (float*)S;
    {
        float bb0 = b_msg[n0 + lq];
        float bb1 = b_msg[n0 + 16 + lq];
        #pragma unroll
        for (int mt = 0; mt < 4; ++mt)
            #pragma unroll
            for (int nt = 0; nt < 2; ++nt) {
                float bb = nt ? bb1 : bb0;
                #pragma unroll
                for (int r = 0; r < 4; ++r) {
                    float v = fmaxf(acc2[mt][nt][r] + bb, 0.f);
                    Msg[(mt * 16 + quad * 4 + r) * 132 + (n0 + nt * 16 + lq)] = v;
                }
            }
    }
    __syncthreads();

    // ---- sorted-segment reduce: run-length sum, one atomic per run ----
    if (tid < 128) {   // thread = column
        int cur = s_dst[0];
        float run = 0.f;
        for (int m = 0; m < 64; ++m) {
            int d = s_dst[m];
            if (d != cur) {
                atomicAdd(msg_sum + (size_t)cur * 128 + tid, run);
                run = 0.f; cur = d;
            }
            run += Msg[m * 132 + tid];
        }
        atomicAdd(msg_sum + (size_t)cur * 128 + tid, run);
    } else if (tid == 128) {   // per-dest edge counts
        int cur = s_dst[0];
        float run = 0.f;
        for (int m = 0; m < 64; ++m) {
            int d = s_dst[m];
            if (d != cur) { atomicAdd(cnt + cur, run); run = 0.f; cur = d; }
            run += 1.f;
        }
        atomicAdd(cnt + cur, run);
    }

    // ---- fused copy node_memory -> out ----
    {
        const float4* s4 = (const float4*)node_memory;
        float4* d4 = (float4*)out;
        const int total4 = (NNODES * 128) / 4;
        const int stride = gridDim.x * 256;
        for (int i = blockIdx.x * 256 + tid; i < total4; i += stride)
            d4[i] = s4[i];
    }
}

// ---------------- destination phase: 16 dests/block ----------------
__global__ __launch_bounds__(256, 4) void dest_kernel(
    const float* __restrict__ node_memory, const float* __restrict__ node_features,
    const int* __restrict__ node_ids,
    const bf16_t* __restrict__ Pr, const bf16_t* __restrict__ Pa,
    const bf16_t* __restrict__ Pu, const bf16_t* __restrict__ Pw,
    const float* __restrict__ b_read, const float* __restrict__ b_agg,
    const float* __restrict__ b_upd, const float* __restrict__ b_write,
    const float* __restrict__ msg_sum, const float* __restrict__ cnt,
    float* __restrict__ out) {

    __shared__ __align__(16) bf16_t B1[16 * 264];  // [mem|feat] -> (agg | upd)
    __shared__ __align__(16) bf16_t B2[16 * 264];  // [dst_read | msg_mean]
    __shared__ int   s_nid[16];
    __shared__ float s_inv[16];

    const int tid = threadIdx.x;
    const int s0  = blockIdx.x * 16;

    if (tid < 16) {
        s_nid[tid] = node_ids[s0 + tid];
        s_inv[tid] = 1.f / fmaxf(cnt[s0 + tid], 1.f);
    }
    __syncthreads();

    // gather [mem|feat] -> B1
    #pragma unroll
    for (int i = 0; i < 4; ++i) {
        int c = i * 256 + tid; int m = c >> 6; int kc = (c & 63) << 2;
        int nrow = s_nid[m];
        float4 v = (kc < 128)
            ? *(const float4*)(node_memory   + (size_t)nrow * 128 + kc)
            : *(const float4*)(node_features + (size_t)nrow * 128 + (kc - 128));
        *(bf16x4*)(B1 + m * 264 + kc) = bf16x4{ (bf16_t)v.x, (bf16_t)v.y, (bf16_t)v.z, (bf16_t)v.w };
    }
    // msg_mean -> B2 cols 128..255
    #pragma unroll
    for (int i = 0; i < 2; ++i) {
        int c = i * 256 + tid; int m = c >> 5; int kc = (c & 31) << 2;
        float4 v = *(const float4*)(msg_sum + (size_t)(s0 + m) * 128 + kc);
        float inv = s_inv[m];
        *(bf16x4*)(B2 + m * 264 + 128 + kc) =
            bf16x4{ (bf16_t)(v.x * inv), (bf16_t)(v.y * inv), (bf16_t)(v.z * inv), (bf16_t)(v.w * inv) };
    }
    __syncthreads();

    const int lane = tid & 63;
    const int w    = tid >> 6;
    const int quad = lane >> 4;
    const int lq   = lane & 15;
    const int n0   = w * 32;

    // GEMM1: [mem|feat] @ W_read -> relu -> B2 cols 0..127
    {
        f32x4 acc[2] = {};
        #pragma unroll
        for (int kb = 0; kb < 8; ++kb) {
            bf16x8 b0 = *(const bf16x8*)(Pr + (((kb * 8 + (w * 2 + 0)) * 64 + lane) << 3));
            bf16x8 b1 = *(const bf16x8*)(Pr + (((kb * 8 + (w * 2 + 1)) * 64 + lane) << 3));
            bf16x8 a  = *(const bf16x8*)(B1 + lq * 264 + kb * 32 + quad * 8);
            acc[0] = __builtin_amdgcn_mfma_f32_16x16x32_bf16(a, b0, acc[0], 0, 0, 0);
            acc[1] = __builtin_amdgcn_mfma_f32_16x16x32_bf16(a, b1, acc[1], 0, 0, 0);
        }
        float bb0 = b_read[n0 + lq], bb1 = b_read[n0 + 16 + lq];
        #pragma unroll
        for (int nt = 0; nt < 2; ++nt) {
            float bb = nt ? bb1 : bb0;
            #pragma unroll
            for (int r = 0; r < 4; ++r) {
                float v = fmaxf(acc[nt][r] + bb, 0.f);
                B2[(quad * 4 + r) * 264 + (n0 + nt * 16 + lq)] = (bf16_t)v;
            }
        }
    }
    __syncthreads();

    // GEMM2: [dst_read|msg_mean] @ W_agg -> relu -> B1 cols 0..127
    {
        f32x4 acc[2] = {};
        #pragma unroll
        for (int kb = 0; kb < 8; ++kb) {
            bf16x8 b0 = *(const bf16x8*)(Pa + (((kb * 8 + (w * 2 + 0)) * 64 + lane) << 3));
            bf16x8 b1 = *(const bf16x8*)(Pa + (((kb * 8 + (w * 2 + 1)) * 64 + lane) << 3));
            bf16x8 a  = *(const bf16x8*)(B2 + lq * 264 + kb * 32 + quad * 8);
            acc[0] = __builtin_amdgcn_mfma_f32_16x16x32_bf16(a, b0, acc[0], 0, 0, 0);
            acc[1] = __builtin_amdgcn_mfma_f32_16x16x32_bf16(a, b1, acc[1], 0, 0, 0);
        }
        float bb0 = b_agg[n0 + lq], bb1 = b_agg[n0 + 16 + lq];
        #pragma unroll
        for (int nt = 0; nt < 2; ++nt) {
            float bb = nt ? bb1 : bb0;
            #pragma unroll
            for (int r = 0; r < 4; ++r) {
                float v = fmaxf(acc[nt][r] + bb, 0.f);
                B1[(quad * 4 + r) * 264 + (n0 + nt * 16 + lq)] = (bf16_t)v;
            }
        }
    }
    __syncthreads();

    // GEMM3: [agg|dst_read] @ W_upd -> relu -> B1 cols 128..255
    {
        f32x4 acc[2] = {};
        #pragma unroll
        for (int kb = 0; kb < 8; ++kb) {
            bf16x8 b0 = *(const bf16x8*)(Pu + (((kb * 8 + (w * 2 + 0)) * 64 + lane) << 3));
            bf16x8 b1 = *(const bf16x8*)(Pu + (((kb * 8 + (w * 2 + 1)) * 64 + lane) << 3));
            bf16x8 a  = (kb < 4)
                ? *(const bf16x8*)(B1 + lq * 264 + kb * 32 + quad * 8)
                : *(const bf16x8*)(B2 + lq * 264 + (kb - 4) * 32 + quad * 8);
            acc[0] = __builtin_amdgcn_mfma_f32_16x16x32_bf16(a, b0, acc[0], 0, 0, 0);
            acc[1] = __builtin_amdgcn_mfma_f32_16x16x32_bf16(a, b1, acc[1], 0, 0, 0);
        }
        float bb0 = b_upd[n0 + lq], bb1 = b_upd[n0 + 16 + lq];
        #pragma unroll
        for (int nt = 0; nt < 2; ++nt) {
            float bb = nt ? bb1 : bb0;
            #pragma unroll
            for (int r = 0; r < 4; ++r) {
                float v = fmaxf(acc[nt][r] + bb, 0.f);
                B1[(quad * 4 + r) * 264 + 128 + (n0 + nt * 16 + lq)] = (bf16_t)v;
            }
        }
    }
    __syncthreads();

    // GEMM4: upd @ W_write (K=128) -> tanh -> scatter to out[node_ids]
    {
        f32x4 acc[2] = {};
        #pragma unroll
        for (int kb = 0; kb < 4; ++kb) {
            bf16x8 b0 = *(const bf16x8*)(Pw + (((kb * 8 + (w * 2 + 0)) * 64 + lane) << 3));
            bf16x8 b1 = *(const bf16x8*)(Pw + (((kb * 8 + (w * 2 + 1)) * 64 + lane) << 3));
            bf16x8 a  = *(const bf16x8*)(B1 + lq * 264 + 128 + kb * 32 + quad * 8);
            acc[0] = __builtin_amdgcn_mfma_f32_16x16x32_bf16(a, b0, acc[0], 0, 0, 0);
            acc[1] = __builtin_amdgcn_mfma_f32_16x16x32_bf16(a, b1, acc[1], 0, 0, 0);
        }
        float bb0 = b_write[n0 + lq], bb1 = b_write[n0 + 16 + lq];
        #pragma unroll
        for (int nt = 0; nt < 2; ++nt) {
            float bb = nt ? bb1 : bb0;
            #pragma unroll
            for (int r = 0; r < 4; ++r) {
                int row = quad * 4 + r;
                int col = n0 + nt * 16 + lq;
                out[(size_t)s_nid[row] * 128 + col] = fast_tanh(acc[nt][r] + bb);
            }
        }
    }
}

extern "C" void kernel_launch(void* const* d_in, const int* in_sizes, int n_in,
                              void* d_out, int out_size, void* d_ws, size_t ws_size,
                              hipStream_t stream) {
    const float* node_memory   = (const float*)d_in[0];
    const float* node_features = (const float*)d_in[1];
    const float* edge_features = (const float*)d_in[2];
    const float* time_enc      = (const float*)d_in[3];
    const int*   source_ids    = (const int*)d_in[5];
    const int*   edge_ids      = (const int*)d_in[6];
    const int*   dest_seg      = (const int*)d_in[7];
    const int*   node_ids      = (const int*)d_in[4];
    const float* W_read  = (const float*)d_in[8];
    const float* b_read  = (const float*)d_in[9];
    const float* W_msg   = (const float*)d_in[10];
    const float* b_msg   = (const float*)d_in[11];
    const float* W_agg   = (const float*)d_in[12];
    const float* b_agg   = (const float*)d_in[13];
    const float* W_upd   = (const float*)d_in[14];
    const float* b_upd   = (const float*)d_in[15];
    const float* W_write = (const float*)d_in[16];
    const float* b_write = (const float*)d_in[17];
    float* out = (float*)d_out;

    char* ws = (char*)d_ws;
    float*  msg_sum = (float*)(ws + 0);                 // 4,194,304 B
    float*  cnt     = (float*)(ws + 4194304);           //    32,768 B
    bf16_t* Pr = (bf16_t*)(ws + 4227072);               //    65,536 B
    bf16_t* Pm = (bf16_t*)(ws + 4292608);               //    57,344 B
    bf16_t* Pa = (bf16_t*)(ws + 4349952);               //    65,536 B
    bf16_t* Pu = (bf16_t*)(ws + 4415488);               //    65,536 B
    bf16_t* Pw = (bf16_t*)(ws + 4481024);               //    32,768 B

    hipMemsetAsync(msg_sum, 0, 4194304 + 32768, stream);   // msg_sum + cnt
    pack_weights_kernel<<<560, 256, 0, stream>>>(W_read, W_msg, W_agg, W_upd, W_write,
                                                 Pr, Pm, Pa, Pu, Pw);
    edge_kernel<<<NEDGE / 64, 256, 0, stream>>>(node_memory, node_features, edge_features,
                                                time_enc, source_ids, edge_ids, dest_seg,
                                                Pr, Pm, b_read, b_msg, msg_sum, cnt, out);
    dest_kernel<<<NDEST / 16, 256, 0, stream>>>(node_memory, node_features, node_ids,
                                                Pr, Pa, Pu, Pw, b_read, b_agg, b_upd, b_write,
                                                msg_sum, cnt, out);
}